// Round 1
// baseline (635.920 us; speedup 1.0000x reference)
//
#include <hip/hip_runtime.h>
#include <hip/hip_bf16.h>

#define IN_F 128
#define HID 256
#define OUT_F 64
#define HEADS 4
#define NEG 0.2f
#define CHUNK 1024

// ---------------- init: zero counters + BN partial sums ----------------
__global__ void k_init(int* cnt, int Nn, float* stats, int ns) {
    int i = blockIdx.x * 256 + threadIdx.x;
    if (i < Nn) cnt[i] = 0;
    if (i < ns) stats[i] = 0.f;
}

// ---------------- GEMM: xh[N,256] = x[N,128] @ Wg[128,256] ----------------
__global__ __launch_bounds__(256) void k_gemm_xh(const float* __restrict__ x,
                                                 const float* __restrict__ Wg,
                                                 float* __restrict__ xh, int Nn) {
    __shared__ float xs[32][IN_F];     // 16 KB
    __shared__ float wsh[32][HID];     // 32 KB
    int t = threadIdx.x;
    int row0 = blockIdx.x * 32;
    for (int i = t; i < 32 * IN_F; i += 256) {
        int r = i >> 7, k = i & 127;
        int gr = row0 + r;
        xs[r][k] = (gr < Nn) ? x[gr * IN_F + k] : 0.f;
    }
    float acc[8][4] = {};
    int tc = t & 63, tr = t >> 6;
    for (int kc = 0; kc < IN_F; kc += 32) {
        __syncthreads();
        for (int i = t; i < 32 * HID; i += 256) {
            int k = i >> 8, c = i & 255;
            wsh[k][c] = Wg[(kc + k) * HID + c];
        }
        __syncthreads();
        for (int k = 0; k < 32; ++k) {
            float wv[4];
#pragma unroll
            for (int j = 0; j < 4; ++j) wv[j] = wsh[k][tc + 64 * j];
#pragma unroll
            for (int r = 0; r < 8; ++r) {
                float xv = xs[tr * 8 + r][kc + k];
#pragma unroll
                for (int j = 0; j < 4; ++j) acc[r][j] += xv * wv[j];
            }
        }
    }
#pragma unroll
    for (int r = 0; r < 8; ++r) {
        int gr = row0 + tr * 8 + r;
        if (gr < Nn) {
#pragma unroll
            for (int j = 0; j < 4; ++j)
                xh[gr * HID + tc + 64 * j] = acc[r][j];
        }
    }
}

// ---------------- attention scalars a_s, a_d ----------------
__global__ void k_att(const float* __restrict__ xh, const float* __restrict__ att_s,
                      const float* __restrict__ att_d, float* __restrict__ a_s,
                      float* __restrict__ a_d, int Nn) {
    int idx = blockIdx.x * 256 + threadIdx.x;   // idx = n*4 + h
    if (idx >= Nn * 4) return;
    int h = idx & 3;
    const float4* xp = (const float4*)(xh + (size_t)idx * 64);
    const float4* sp = (const float4*)(att_s + h * 64);
    const float4* dp = (const float4*)(att_d + h * 64);
    float ss = 0.f, dd = 0.f;
#pragma unroll
    for (int q = 0; q < 16; ++q) {
        float4 v = xp[q], s = sp[q], d = dp[q];
        ss += v.x * s.x + v.y * s.y + v.z * s.z + v.w * s.w;
        dd += v.x * d.x + v.y * d.y + v.z * d.z + v.w * d.w;
    }
    a_s[idx] = ss;
    a_d[idx] = dd;
}

// ---------------- CSR build ----------------
__global__ void k_hist(const int* __restrict__ dst, int E, int* cnt) {
    int e = blockIdx.x * 256 + threadIdx.x;
    if (e < E) atomicAdd(&cnt[dst[e]], 1);
}

__global__ __launch_bounds__(1024) void k_scan(const int* __restrict__ cnt, int Nn,
                                               int* row_ptr, int* cursor) {
    __shared__ int buf[1024];
    __shared__ int s_run;
    int t = threadIdx.x;
    if (t == 0) s_run = 0;
    __syncthreads();
    for (int base = 0; base < Nn; base += 1024) {
        int v = (base + t < Nn) ? cnt[base + t] : 0;
        buf[t] = v;
        __syncthreads();
        for (int off = 1; off < 1024; off <<= 1) {
            int add = (t >= off) ? buf[t - off] : 0;
            __syncthreads();
            buf[t] += add;
            __syncthreads();
        }
        int run = s_run;
        if (base + t < Nn) {
            int ex = run + buf[t] - v;
            row_ptr[base + t] = ex;
            cursor[base + t] = ex;
        }
        __syncthreads();
        if (t == 1023) s_run = run + buf[1023];
        __syncthreads();
    }
    if (t == 0) row_ptr[Nn] = s_run;
}

__global__ void k_scatter(const int* __restrict__ src, const int* __restrict__ dst,
                          int E, int* cursor, int* col) {
    int e = blockIdx.x * 256 + threadIdx.x;
    if (e < E) {
        int d = dst[e];
        int pos = atomicAdd(&cursor[d], 1);
        col[pos] = src[e];
    }
}

// ---------------- the big one: per-node GAT aggregation ----------------
__global__ __launch_bounds__(256) void k_gat(const int* __restrict__ row_ptr,
                                             const int* __restrict__ col,
                                             const float* __restrict__ xh,
                                             const float* __restrict__ a_s,
                                             const float* __restrict__ a_d,
                                             const float* __restrict__ bias,
                                             float* __restrict__ hg, int Nn) {
    int i = blockIdx.x;
    int t = threadIdx.x;
    int beg = row_ptr[i], end = row_ptr[i + 1];

    __shared__ int cols[CHUNK];        // 4 KB
    __shared__ float wv[CHUNK * 4];    // 16 KB
    __shared__ float red[64][4];       // 1 KB
    __shared__ float sh_m[4], sh_inv[4], sh_ad[4], sh_asl[4];

    if (t < 4) { sh_ad[t] = a_d[i * 4 + t]; sh_asl[t] = a_s[i * 4 + t]; }
    __syncthreads();

    int h = t & 3, q = t >> 2;
    float adh = sh_ad[h];
    float eself = sh_asl[h] + adh;
    eself = eself > 0.f ? eself : NEG * eself;

    // -------- phase 1: per-head max --------
    float lm = -1e30f;
    for (int cb = beg; cb < end; cb += CHUNK) {
        int n = min(CHUNK, end - cb);
        __syncthreads();
        for (int j = t; j < n; j += 256) cols[j] = col[cb + j];
        __syncthreads();
        for (int j = q; j < n; j += 64) {
            float e = a_s[cols[j] * 4 + h] + adh;
            e = e > 0.f ? e : NEG * e;
            lm = fmaxf(lm, e);
        }
    }
    red[q][h] = lm;
    __syncthreads();
    for (int s = 32; s > 0; s >>= 1) {
        if (q < s) red[q][h] = fmaxf(red[q][h], red[q + s][h]);
        __syncthreads();
    }
    float m = fmaxf(red[0][h], eself);
    __syncthreads();

    // -------- phase 2: per-head denom --------
    float ls = (q == 0) ? __expf(eself - m) : 0.f;
    for (int cb = beg; cb < end; cb += CHUNK) {
        int n = min(CHUNK, end - cb);
        __syncthreads();
        for (int j = t; j < n; j += 256) cols[j] = col[cb + j];
        __syncthreads();
        for (int j = q; j < n; j += 64) {
            float e = a_s[cols[j] * 4 + h] + adh;
            e = e > 0.f ? e : NEG * e;
            ls += __expf(e - m);
        }
    }
    red[q][h] = ls;
    __syncthreads();
    for (int s = 32; s > 0; s >>= 1) {
        if (q < s) red[q][h] += red[q + s][h];
        __syncthreads();
    }
    float inv = 1.f / (red[0][h] + 1e-16f);
    if (q == 0) { sh_m[h] = m; sh_inv[h] = inv; }
    __syncthreads();

    // -------- phase 3: weighted accumulate --------
    int hc = t >> 6;   // head for this output channel
    float eselfc = sh_asl[hc] + sh_ad[hc];
    eselfc = eselfc > 0.f ? eselfc : NEG * eselfc;
    float acc = __expf(eselfc - sh_m[hc]) * sh_inv[hc] * xh[(size_t)i * HID + t];

    for (int cb = beg; cb < end; cb += CHUNK) {
        int n = min(CHUNK, end - cb);
        __syncthreads();
        for (int j = t; j < n; j += 256) cols[j] = col[cb + j];
        __syncthreads();
        // parallel precompute of alpha for all (edge, head)
        for (int idx = t; idx < n * 4; idx += 256) {
            int j = idx >> 2, hh = idx & 3;
            float e = a_s[cols[j] * 4 + hh] + sh_ad[hh];
            e = e > 0.f ? e : NEG * e;
            wv[idx] = __expf(e - sh_m[hh]) * sh_inv[hh];
        }
        __syncthreads();
#pragma unroll 4
        for (int j = 0; j < n; ++j) {
            acc += wv[j * 4 + hc] * xh[(size_t)cols[j] * HID + t];
        }
    }
    hg[(size_t)i * HID + t] = acc + bias[t];
}

// ---------------- BN stats (2-level) ----------------
__global__ void k_bnstat(const float* __restrict__ h, int Nn, int C,
                         float* __restrict__ sums) {
    int t = threadIdx.x;           // t < C (blockDim == C)
    int rows_per = (Nn + gridDim.x - 1) / gridDim.x;
    int r0 = blockIdx.x * rows_per;
    int r1 = min(Nn, r0 + rows_per);
    float s = 0.f, sq = 0.f;
    for (int r = r0; r < r1; ++r) {
        float v = h[(size_t)r * C + t];
        s += v;
        sq += v * v;
    }
    atomicAdd(&sums[t], s);
    atomicAdd(&sums[C + t], sq);
}

__global__ void k_bnfin(const float* __restrict__ sums, int C, float Ninv,
                        const float* __restrict__ gamma, const float* __restrict__ beta,
                        float* __restrict__ scale, float* __restrict__ shift) {
    int t = threadIdx.x;
    if (t >= C) return;
    float mu = sums[t] * Ninv;
    float var = sums[C + t] * Ninv - mu * mu;
    float a = gamma[t] * rsqrtf(var + 1e-5f);
    scale[t] = a;
    shift[t] = beta[t] - mu * a;
}

// ---------------- Linear: h2 = relu(bn1(hg)) @ Wl + bl ----------------
__global__ __launch_bounds__(256) void k_lin(const float* __restrict__ hg,
                                             const float* __restrict__ scale1,
                                             const float* __restrict__ shift1,
                                             const float* __restrict__ Wl,
                                             const float* __restrict__ bl,
                                             float* __restrict__ h2, int Nn) {
    __shared__ float hs[32][64];   // 8 KB
    __shared__ float wsh[64][64];  // 16 KB
    int t = threadIdx.x;
    int row0 = blockIdx.x * 32;
    int tc = t & 63, tr = t >> 6;
    float acc[8] = {};
    for (int kc = 0; kc < HID; kc += 64) {
        __syncthreads();
        for (int i = t; i < 32 * 64; i += 256) {
            int r = i >> 6, k = i & 63;
            int gr = row0 + r;
            float v = (gr < Nn) ? hg[(size_t)gr * HID + kc + k] : 0.f;
            v = v * scale1[kc + k] + shift1[kc + k];
            hs[r][k] = v > 0.f ? v : 0.f;
        }
        for (int i = t; i < 64 * 64; i += 256) {
            int k = i >> 6, c = i & 63;
            wsh[k][c] = Wl[(kc + k) * OUT_F + c];
        }
        __syncthreads();
        for (int k = 0; k < 64; ++k) {
            float w = wsh[k][tc];
#pragma unroll
            for (int r = 0; r < 8; ++r) acc[r] += hs[tr * 8 + r][k] * w;
        }
    }
#pragma unroll
    for (int r = 0; r < 8; ++r) {
        int gr = row0 + tr * 8 + r;
        if (gr < Nn) h2[(size_t)gr * OUT_F + tc] = acc[r] + bl[tc];
    }
}

// ---------------- final BN2 apply + relu ----------------
__global__ void k_out(const float* __restrict__ h2, const float* __restrict__ scale2,
                      const float* __restrict__ shift2, float* __restrict__ out, int total) {
    int i = blockIdx.x * 256 + threadIdx.x;
    if (i >= total) return;
    int c = i & 63;
    float v = h2[i] * scale2[c] + shift2[c];
    out[i] = v > 0.f ? v : 0.f;
}

extern "C" void kernel_launch(void* const* d_in, const int* in_sizes, int n_in,
                              void* d_out, int out_size, void* d_ws, size_t ws_size,
                              hipStream_t stream) {
    const float* x     = (const float*)d_in[0];
    const float* Wg    = (const float*)d_in[2];
    const float* att_s = (const float*)d_in[3];
    const float* att_d = (const float*)d_in[4];
    const float* bias_g= (const float*)d_in[5];
    const float* g1    = (const float*)d_in[6];
    const float* b1    = (const float*)d_in[7];
    const float* Wl    = (const float*)d_in[8];
    const float* bl    = (const float*)d_in[9];
    const float* g2    = (const float*)d_in[10];
    const float* b2    = (const float*)d_in[11];
    const int*   ei    = (const int*)d_in[12];

    const int N = in_sizes[0] / IN_F;
    const int E = in_sizes[12] / 2;
    const int* e_src = ei;
    const int* e_dst = ei + E;

    // -------- workspace carving --------
    char* wsb = (char*)d_ws;
    size_t o = 0;
    auto take = [&](size_t bytes) -> void* {
        void* p = wsb + o;
        o = (o + bytes + 255) & ~(size_t)255;
        return p;
    };
    float* xh      = (float*)take((size_t)N * HID * 4);
    float* hg      = (float*)take((size_t)N * HID * 4);
    float* h2      = (float*)take((size_t)N * OUT_F * 4);
    float* a_s     = (float*)take((size_t)N * 4 * 4);
    float* a_d     = (float*)take((size_t)N * 4 * 4);
    int*   row_ptr = (int*)take((size_t)(N + 1) * 4);
    int*   cnt     = (int*)take((size_t)N * 4);
    int*   cursor  = (int*)take((size_t)N * 4);
    int*   colidx  = (int*)take((size_t)E * 4);
    float* stats   = (float*)take(2048 * 4);
    // stats layout: [0..511] bn1 sum/sumsq, [512..639] bn2 sum/sumsq,
    //               [640..895] scale1, [896..1151] shift1, [1152..1215] scale2, [1216..1279] shift2
    float* bn1s = stats;
    float* bn2s = stats + 512;
    float* sc1  = stats + 640;
    float* sf1  = stats + 896;
    float* sc2  = stats + 1152;
    float* sf2  = stats + 1216;

    float* out = (float*)d_out;

    // 1) init counters / stats
    k_init<<<(N + 255) / 256, 256, 0, stream>>>(cnt, N, stats, 640);
    // 2) xh GEMM
    k_gemm_xh<<<(N + 31) / 32, 256, 0, stream>>>(x, Wg, xh, N);
    // 3) attention scalars
    k_att<<<(N * 4 + 255) / 256, 256, 0, stream>>>(xh, att_s, att_d, a_s, a_d, N);
    // 4) CSR build
    k_hist<<<(E + 255) / 256, 256, 0, stream>>>(e_dst, E, cnt);
    k_scan<<<1, 1024, 0, stream>>>(cnt, N, row_ptr, cursor);
    k_scatter<<<(E + 255) / 256, 256, 0, stream>>>(e_src, e_dst, E, cursor, colidx);
    // 5) GAT aggregation
    k_gat<<<N, 256, 0, stream>>>(row_ptr, colidx, xh, a_s, a_d, bias_g, hg, N);
    // 6) BN1 stats + finalize
    k_bnstat<<<256, HID, 0, stream>>>(hg, N, HID, bn1s);
    k_bnfin<<<1, HID, 0, stream>>>(bn1s, HID, 1.0f / N, g1, b1, sc1, sf1);
    // 7) Linear
    k_lin<<<(N + 31) / 32, 256, 0, stream>>>(hg, sc1, sf1, Wl, bl, h2, N);
    // 8) BN2 stats + finalize
    k_bnstat<<<256, OUT_F, 0, stream>>>(h2, N, OUT_F, bn2s);
    k_bnfin<<<1, OUT_F, 0, stream>>>(bn2s, OUT_F, 1.0f / N, g2, b2, sc2, sf2);
    // 9) output
    k_out<<<(N * OUT_F + 255) / 256, 256, 0, stream>>>(h2, sc2, sf2, out, N * OUT_F);
}

// Round 2
// 489.805 us; speedup vs baseline: 1.2983x; 1.2983x over previous
//
#include <hip/hip_runtime.h>
#include <hip/hip_bf16.h>

#define IN_F 128
#define HID 256
#define OUT_F 64
#define HEADS 4
#define NEG 0.2f

__device__ __forceinline__ float lrelu(float v) { return v > 0.f ? v : NEG * v; }

// ---------------- init: zero counters + BN partial sums ----------------
__global__ void k_init(int* cnt, int Nn, float* stats, int ns) {
    int i = blockIdx.x * 256 + threadIdx.x;
    if (i < Nn) cnt[i] = 0;
    if (i < ns) stats[i] = 0.f;
}

// ---------------- GEMM: xh[N,256] = x[N,128] @ Wg[128,256] ----------------
__global__ __launch_bounds__(256) void k_gemm_xh(const float* __restrict__ x,
                                                 const float* __restrict__ Wg,
                                                 float* __restrict__ xh, int Nn) {
    __shared__ float xs[32][IN_F];     // 16 KB
    __shared__ float wsh[32][HID];     // 32 KB
    int t = threadIdx.x;
    int row0 = blockIdx.x * 32;
    for (int i = t; i < 32 * IN_F; i += 256) {
        int r = i >> 7, k = i & 127;
        int gr = row0 + r;
        xs[r][k] = (gr < Nn) ? x[gr * IN_F + k] : 0.f;
    }
    float acc[8][4] = {};
    int tc = t & 63, tr = t >> 6;
    for (int kc = 0; kc < IN_F; kc += 32) {
        __syncthreads();
        for (int i = t; i < 32 * HID; i += 256) {
            int k = i >> 8, c = i & 255;
            wsh[k][c] = Wg[(kc + k) * HID + c];
        }
        __syncthreads();
        for (int k = 0; k < 32; ++k) {
            float wv[4];
#pragma unroll
            for (int j = 0; j < 4; ++j) wv[j] = wsh[k][tc + 64 * j];
#pragma unroll
            for (int r = 0; r < 8; ++r) {
                float xv = xs[tr * 8 + r][kc + k];
#pragma unroll
                for (int j = 0; j < 4; ++j) acc[r][j] += xv * wv[j];
            }
        }
    }
#pragma unroll
    for (int r = 0; r < 8; ++r) {
        int gr = row0 + tr * 8 + r;
        if (gr < Nn) {
#pragma unroll
            for (int j = 0; j < 4; ++j)
                xh[gr * HID + tc + 64 * j] = acc[r][j];
        }
    }
}

// ---------------- attention scalars a_s, a_d ----------------
__global__ void k_att(const float* __restrict__ xh, const float* __restrict__ att_s,
                      const float* __restrict__ att_d, float* __restrict__ a_s,
                      float* __restrict__ a_d, int Nn) {
    int idx = blockIdx.x * 256 + threadIdx.x;   // idx = n*4 + h
    if (idx >= Nn * 4) return;
    int h = idx & 3;
    const float4* xp = (const float4*)(xh + (size_t)idx * 64);
    const float4* sp = (const float4*)(att_s + h * 64);
    const float4* dp = (const float4*)(att_d + h * 64);
    float ss = 0.f, dd = 0.f;
#pragma unroll
    for (int q = 0; q < 16; ++q) {
        float4 v = xp[q], s = sp[q], d = dp[q];
        ss += v.x * s.x + v.y * s.y + v.z * s.z + v.w * s.w;
        dd += v.x * d.x + v.y * d.y + v.z * d.z + v.w * d.w;
    }
    a_s[idx] = ss;
    a_d[idx] = dd;
}

// ---------------- CSR build ----------------
__global__ void k_hist(const int* __restrict__ dst, int E, int* cnt) {
    int e = blockIdx.x * 256 + threadIdx.x;
    if (e < E) atomicAdd(&cnt[dst[e]], 1);
}

// hierarchical scan: per-block sums -> scan sums -> per-block rescan
__global__ void k_scan1(const int* __restrict__ cnt, int Nn, int* bsum) {
    int b = blockIdx.x, t = threadIdx.x;
    int idx = b * 256 + t;
    int v = (idx < Nn) ? cnt[idx] : 0;
#pragma unroll
    for (int off = 32; off; off >>= 1) v += __shfl_down(v, off);
    __shared__ int ws[4];
    if ((t & 63) == 0) ws[t >> 6] = v;
    __syncthreads();
    if (t == 0) bsum[b] = ws[0] + ws[1] + ws[2] + ws[3];
}

__global__ void k_scan2(int* bsum, int nb, int* total) {
    __shared__ int buf[256];
    int t = threadIdx.x;
    int v = (t < nb) ? bsum[t] : 0;
    buf[t] = v;
    __syncthreads();
    for (int off = 1; off < 256; off <<= 1) {
        int a = (t >= off) ? buf[t - off] : 0;
        __syncthreads();
        buf[t] += a;
        __syncthreads();
    }
    if (t < nb) bsum[t] = buf[t] - v;      // exclusive
    if (t == nb - 1) *total = buf[t];      // grand total -> row_ptr[N]
}

__global__ void k_scan3(const int* __restrict__ cnt, int Nn, const int* __restrict__ bsum,
                        int* row_ptr, int* cursor) {
    __shared__ int buf[256];
    int b = blockIdx.x, t = threadIdx.x, idx = b * 256 + t;
    int v = (idx < Nn) ? cnt[idx] : 0;
    buf[t] = v;
    __syncthreads();
    for (int off = 1; off < 256; off <<= 1) {
        int a = (t >= off) ? buf[t - off] : 0;
        __syncthreads();
        buf[t] += a;
        __syncthreads();
    }
    if (idx < Nn) {
        int ex = bsum[b] + buf[t] - v;
        row_ptr[idx] = ex;
        cursor[idx] = ex;
    }
}

__global__ void k_scatter(const int* __restrict__ src, const int* __restrict__ dst,
                          int E, int* cursor, int* col) {
    int e = blockIdx.x * 256 + threadIdx.x;
    if (e < E) {
        int d = dst[e];
        int pos = atomicAdd(&cursor[d], 1);
        col[pos] = src[e];
    }
}

// ---------------- GAT aggregation: one wave per node ----------------
__global__ __launch_bounds__(256) void k_gat(const int* __restrict__ row_ptr,
                                             const int* __restrict__ col,
                                             const float* __restrict__ xh,
                                             const float* __restrict__ a_s,
                                             const float* __restrict__ a_d,
                                             const float* __restrict__ bias,
                                             float* __restrict__ hg, int Nn) {
    int w = threadIdx.x >> 6, lane = threadIdx.x & 63;
    int i = blockIdx.x * 4 + w;
    if (i >= Nn) return;
    int beg = row_ptr[i], end = row_ptr[i + 1];

    float4 ad = *(const float4*)(a_d + 4 * (size_t)i);
    float4 as = *(const float4*)(a_s + 4 * (size_t)i);
    float4 es;
    es.x = lrelu(as.x + ad.x); es.y = lrelu(as.y + ad.y);
    es.z = lrelu(as.z + ad.z); es.w = lrelu(as.w + ad.w);

    // ---- pass 1: per-head max over edges (+ self) ----
    float4 m = es;
    for (int j = beg + lane; j < end; j += 64) {
        int c = col[j];
        float4 t = *(const float4*)(a_s + 4 * (size_t)c);
        m.x = fmaxf(m.x, lrelu(t.x + ad.x));
        m.y = fmaxf(m.y, lrelu(t.y + ad.y));
        m.z = fmaxf(m.z, lrelu(t.z + ad.z));
        m.w = fmaxf(m.w, lrelu(t.w + ad.w));
    }
#pragma unroll
    for (int off = 32; off; off >>= 1) {
        m.x = fmaxf(m.x, __shfl_xor(m.x, off));
        m.y = fmaxf(m.y, __shfl_xor(m.y, off));
        m.z = fmaxf(m.z, __shfl_xor(m.z, off));
        m.w = fmaxf(m.w, __shfl_xor(m.w, off));
    }

    int hc = lane >> 4;   // head served by this lane's 4 channels
    float mh = hc < 2 ? (hc == 0 ? m.x : m.y) : (hc == 2 ? m.z : m.w);
    float eh = hc < 2 ? (hc == 0 ? es.x : es.y) : (hc == 2 ? es.z : es.w);
    float ps = __expf(eh - mh);   // self-loop weight (unnormalized)

    // ---- pass 2: fused unnormalized accumulate + denominator ----
    float4 acc = *(const float4*)(xh + (size_t)i * HID + lane * 4);
    acc.x *= ps; acc.y *= ps; acc.z *= ps; acc.w *= ps;

    float4 dl = make_float4(0.f, 0.f, 0.f, 0.f);   // per-lane partial denominators

    for (int cb = beg; cb < end; cb += 64) {
        int n = min(64, end - cb);
        int c = 0;
        float4 p = make_float4(0.f, 0.f, 0.f, 0.f);
        if (lane < n) {
            c = col[cb + lane];
            float4 t = *(const float4*)(a_s + 4 * (size_t)c);
            p.x = __expf(lrelu(t.x + ad.x) - m.x);
            p.y = __expf(lrelu(t.y + ad.y) - m.y);
            p.z = __expf(lrelu(t.z + ad.z) - m.z);
            p.w = __expf(lrelu(t.w + ad.w) - m.w);
            dl.x += p.x; dl.y += p.y; dl.z += p.z; dl.w += p.w;
        }
#pragma unroll 4
        for (int j = 0; j < n; ++j) {
            int cj = __shfl(c, j);
            float p0 = __shfl(p.x, j);
            float p1 = __shfl(p.y, j);
            float p2 = __shfl(p.z, j);
            float p3 = __shfl(p.w, j);
            float pj = hc < 2 ? (hc == 0 ? p0 : p1) : (hc == 2 ? p2 : p3);
            const float4 xv = *(const float4*)(xh + (size_t)cj * HID + lane * 4);
            acc.x += pj * xv.x;
            acc.y += pj * xv.y;
            acc.z += pj * xv.z;
            acc.w += pj * xv.w;
        }
    }

    // reduce denominators across lanes, add self term
#pragma unroll
    for (int off = 32; off; off >>= 1) {
        dl.x += __shfl_xor(dl.x, off);
        dl.y += __shfl_xor(dl.y, off);
        dl.z += __shfl_xor(dl.z, off);
        dl.w += __shfl_xor(dl.w, off);
    }
    float dh = hc < 2 ? (hc == 0 ? dl.x : dl.y) : (hc == 2 ? dl.z : dl.w);
    float inv = 1.f / (dh + ps + 1e-16f);

    float4 b4 = *(const float4*)(bias + lane * 4);
    float4 o;
    o.x = acc.x * inv + b4.x;
    o.y = acc.y * inv + b4.y;
    o.z = acc.z * inv + b4.z;
    o.w = acc.w * inv + b4.w;
    *(float4*)(hg + (size_t)i * HID + lane * 4) = o;
}

// ---------------- BN stats (2-level) ----------------
__global__ void k_bnstat(const float* __restrict__ h, int Nn, int C,
                         float* __restrict__ sums) {
    int t = threadIdx.x;           // t < C (blockDim == C)
    int rows_per = (Nn + gridDim.x - 1) / gridDim.x;
    int r0 = blockIdx.x * rows_per;
    int r1 = min(Nn, r0 + rows_per);
    float s = 0.f, sq = 0.f;
    for (int r = r0; r < r1; ++r) {
        float v = h[(size_t)r * C + t];
        s += v;
        sq += v * v;
    }
    atomicAdd(&sums[t], s);
    atomicAdd(&sums[C + t], sq);
}

__global__ void k_bnfin(const float* __restrict__ sums, int C, float Ninv,
                        const float* __restrict__ gamma, const float* __restrict__ beta,
                        float* __restrict__ scale, float* __restrict__ shift) {
    int t = threadIdx.x;
    if (t >= C) return;
    float mu = sums[t] * Ninv;
    float var = sums[C + t] * Ninv - mu * mu;
    float a = gamma[t] * rsqrtf(var + 1e-5f);
    scale[t] = a;
    shift[t] = beta[t] - mu * a;
}

// ---------------- Linear: h2 = relu(bn1(hg)) @ Wl + bl ----------------
__global__ __launch_bounds__(256) void k_lin(const float* __restrict__ hg,
                                             const float* __restrict__ scale1,
                                             const float* __restrict__ shift1,
                                             const float* __restrict__ Wl,
                                             const float* __restrict__ bl,
                                             float* __restrict__ h2, int Nn) {
    __shared__ float hs[32][64];   // 8 KB
    __shared__ float wsh[64][64];  // 16 KB
    int t = threadIdx.x;
    int row0 = blockIdx.x * 32;
    int tc = t & 63, tr = t >> 6;
    float acc[8] = {};
    for (int kc = 0; kc < HID; kc += 64) {
        __syncthreads();
        for (int i = t; i < 32 * 64; i += 256) {
            int r = i >> 6, k = i & 63;
            int gr = row0 + r;
            float v = (gr < Nn) ? hg[(size_t)gr * HID + kc + k] : 0.f;
            v = v * scale1[kc + k] + shift1[kc + k];
            hs[r][k] = v > 0.f ? v : 0.f;
        }
        for (int i = t; i < 64 * 64; i += 256) {
            int k = i >> 6, c = i & 63;
            wsh[k][c] = Wl[(kc + k) * OUT_F + c];
        }
        __syncthreads();
        for (int k = 0; k < 64; ++k) {
            float w = wsh[k][tc];
#pragma unroll
            for (int r = 0; r < 8; ++r) acc[r] += hs[tr * 8 + r][k] * w;
        }
    }
#pragma unroll
    for (int r = 0; r < 8; ++r) {
        int gr = row0 + tr * 8 + r;
        if (gr < Nn) h2[(size_t)gr * OUT_F + tc] = acc[r] + bl[tc];
    }
}

// ---------------- final BN2 apply + relu ----------------
__global__ void k_out(const float* __restrict__ h2, const float* __restrict__ scale2,
                      const float* __restrict__ shift2, float* __restrict__ out, int total) {
    int i = blockIdx.x * 256 + threadIdx.x;
    if (i >= total) return;
    int c = i & 63;
    float v = h2[i] * scale2[c] + shift2[c];
    out[i] = v > 0.f ? v : 0.f;
}

extern "C" void kernel_launch(void* const* d_in, const int* in_sizes, int n_in,
                              void* d_out, int out_size, void* d_ws, size_t ws_size,
                              hipStream_t stream) {
    const float* x     = (const float*)d_in[0];
    const float* Wg    = (const float*)d_in[2];
    const float* att_s = (const float*)d_in[3];
    const float* att_d = (const float*)d_in[4];
    const float* bias_g= (const float*)d_in[5];
    const float* g1    = (const float*)d_in[6];
    const float* b1    = (const float*)d_in[7];
    const float* Wl    = (const float*)d_in[8];
    const float* bl    = (const float*)d_in[9];
    const float* g2    = (const float*)d_in[10];
    const float* b2    = (const float*)d_in[11];
    const int*   ei    = (const int*)d_in[12];

    const int N = in_sizes[0] / IN_F;
    const int E = in_sizes[12] / 2;
    const int* e_src = ei;
    const int* e_dst = ei + E;
    const int NB = (N + 255) / 256;   // scan blocks

    // -------- workspace carving --------
    char* wsb = (char*)d_ws;
    size_t o = 0;
    auto take = [&](size_t bytes) -> void* {
        void* p = wsb + o;
        o = (o + bytes + 255) & ~(size_t)255;
        return p;
    };
    float* xh      = (float*)take((size_t)N * HID * 4);
    float* hg      = (float*)take((size_t)N * HID * 4);
    float* h2      = (float*)take((size_t)N * OUT_F * 4);
    float* a_s     = (float*)take((size_t)N * 4 * 4);
    float* a_d     = (float*)take((size_t)N * 4 * 4);
    int*   row_ptr = (int*)take((size_t)(N + 1) * 4);
    int*   cnt     = (int*)take((size_t)N * 4);
    int*   cursor  = (int*)take((size_t)N * 4);
    int*   colidx  = (int*)take((size_t)E * 4);
    int*   bsum    = (int*)take((size_t)NB * 4);
    float* stats   = (float*)take(2048 * 4);
    float* bn1s = stats;
    float* bn2s = stats + 512;
    float* sc1  = stats + 640;
    float* sf1  = stats + 896;
    float* sc2  = stats + 1152;
    float* sf2  = stats + 1216;

    float* out = (float*)d_out;

    // 1) init counters / stats
    k_init<<<(N + 255) / 256, 256, 0, stream>>>(cnt, N, stats, 640);
    // 2) xh GEMM
    k_gemm_xh<<<(N + 31) / 32, 256, 0, stream>>>(x, Wg, xh, N);
    // 3) attention scalars
    k_att<<<(N * 4 + 255) / 256, 256, 0, stream>>>(xh, att_s, att_d, a_s, a_d, N);
    // 4) CSR build
    k_hist<<<(E + 255) / 256, 256, 0, stream>>>(e_dst, E, cnt);
    k_scan1<<<NB, 256, 0, stream>>>(cnt, N, bsum);
    k_scan2<<<1, 256, 0, stream>>>(bsum, NB, row_ptr + N);
    k_scan3<<<NB, 256, 0, stream>>>(cnt, N, bsum, row_ptr, cursor);
    k_scatter<<<(E + 255) / 256, 256, 0, stream>>>(e_src, e_dst, E, cursor, colidx);
    // 5) GAT aggregation (wave per node)
    k_gat<<<(N + 3) / 4, 256, 0, stream>>>(row_ptr, colidx, xh, a_s, a_d, bias_g, hg, N);
    // 6) BN1 stats + finalize
    k_bnstat<<<256, HID, 0, stream>>>(hg, N, HID, bn1s);
    k_bnfin<<<1, HID, 0, stream>>>(bn1s, HID, 1.0f / N, g1, b1, sc1, sf1);
    // 7) Linear
    k_lin<<<(N + 31) / 32, 256, 0, stream>>>(hg, sc1, sf1, Wl, bl, h2, N);
    // 8) BN2 stats + finalize
    k_bnstat<<<256, OUT_F, 0, stream>>>(h2, N, OUT_F, bn2s);
    k_bnfin<<<1, OUT_F, 0, stream>>>(bn2s, OUT_F, 1.0f / N, g2, b2, sc2, sf2);
    // 9) output
    k_out<<<(N * OUT_F + 255) / 256, 256, 0, stream>>>(h2, sc2, sf2, out, N * OUT_F);
}

// Round 4
// 363.266 us; speedup vs baseline: 1.7506x; 1.3483x over previous
//
#include <hip/hip_runtime.h>
#include <hip/hip_bf16.h>

#define IN_F 128
#define HID 256
#define OUT_F 64
#define NEG 0.2f

typedef __attribute__((ext_vector_type(8))) short bf16x8;
typedef __attribute__((ext_vector_type(4))) float f32x4;

__device__ __forceinline__ float lrelu(float v) { return v > 0.f ? v : NEG * v; }
__device__ __forceinline__ float bf2f(ushort u) { return __uint_as_float((uint)u << 16); }
__device__ __forceinline__ ushort f2bf(float f) {
    uint i = __float_as_uint(f);
    i += 0x7fffu + ((i >> 16) & 1u);
    return (ushort)(i >> 16);
}

// ---------------- init ----------------
__global__ void k_init(int* cnt, int Nn, float* stats, int ns) {
    int i = blockIdx.x * 256 + threadIdx.x;
    if (i < Nn) cnt[i] = 0;
    if (i < ns) stats[i] = 0.f;
}

// ---------------- casts ----------------
__global__ void k_cast_x(const float* __restrict__ x, ushort* __restrict__ xb, int total4) {
    int i = blockIdx.x * 256 + threadIdx.x;
    if (i >= total4) return;
    float4 v = ((const float4*)x)[i];
    ((ushort4*)xb)[i] = make_ushort4(f2bf(v.x), f2bf(v.y), f2bf(v.z), f2bf(v.w));
}

// transpose + cast both weight matrices (small)
__global__ void k_cast_w(const float* __restrict__ Wg, const float* __restrict__ Wl,
                         ushort* __restrict__ Wgt, ushort* __restrict__ Wlt) {
    int i = blockIdx.x * 256 + threadIdx.x;
    if (i < IN_F * HID) {               // Wgt[c][k] = Wg[k][c], c<256,k<128
        int c = i >> 7, k = i & 127;
        Wgt[i] = f2bf(Wg[k * HID + c]);
    }
    int j = i - IN_F * HID;
    if (j >= 0 && j < OUT_F * HID) {    // Wlt[c][k] = Wl[k][c], c<64,k<256
        int c = j >> 8, k = j & 255;
        Wlt[j] = f2bf(Wl[k * OUT_F + c]);
    }
}

// ---------------- MFMA GEMM: xhb[N,256](bf16) = xb[N,128] @ Wg[128,256] ----------------
__global__ __launch_bounds__(256) void k_gemm_xh(const ushort* __restrict__ xb,
                                                 const ushort* __restrict__ Wgt,
                                                 ushort* __restrict__ xhb, int Nn) {
    __shared__ ushort Alds[64][136];   // 64 rows x 128 k, +8 pad -> 2-way bank (free)
    int t = threadIdx.x;
    int w = t >> 6, lane = t & 63;
    int row0 = blockIdx.x * 64;

    // stage A: 64 rows x 128 bf16 = 1024 x 16B chunks (FIXED: was 512 -> half-staged)
#pragma unroll
    for (int i = t; i < 1024; i += 256) {
        int r = i >> 4, c = i & 15;
        int gr = row0 + r;
        uint4 v = make_uint4(0u, 0u, 0u, 0u);
        if (gr < Nn) v = *(const uint4*)(xb + (size_t)gr * IN_F + c * 8);
        *(uint4*)(&Alds[r][c * 8]) = v;
    }

    int qw = lane >> 4, lr = lane & 15;
    // B-frags in registers: wave w covers cols [64w, 64w+64)
    bf16x8 bf[4][4];
#pragma unroll
    for (int ct = 0; ct < 4; ++ct)
#pragma unroll
        for (int kt = 0; kt < 4; ++kt) {
            int col = w * 64 + ct * 16 + lr;
            bf[ct][kt] = *(const bf16x8*)(Wgt + (size_t)col * IN_F + kt * 32 + qw * 8);
        }

    f32x4 zero = {0.f, 0.f, 0.f, 0.f};
    f32x4 acc[4][4];
#pragma unroll
    for (int rt = 0; rt < 4; ++rt)
#pragma unroll
        for (int ct = 0; ct < 4; ++ct) acc[rt][ct] = zero;

    __syncthreads();
#pragma unroll
    for (int kt = 0; kt < 4; ++kt) {
#pragma unroll
        for (int rt = 0; rt < 4; ++rt) {
            bf16x8 af = *(const bf16x8*)(&Alds[rt * 16 + lr][kt * 32 + qw * 8]);
#pragma unroll
            for (int ct = 0; ct < 4; ++ct)
                acc[rt][ct] = __builtin_amdgcn_mfma_f32_16x16x32_bf16(af, bf[ct][kt], acc[rt][ct], 0, 0, 0);
        }
    }

    // epilogue: D row=(lane>>4)*4+reg, col=lane&15
#pragma unroll
    for (int rt = 0; rt < 4; ++rt)
#pragma unroll
        for (int ct = 0; ct < 4; ++ct)
#pragma unroll
            for (int r = 0; r < 4; ++r) {
                int row = row0 + rt * 16 + qw * 4 + r;
                if (row < Nn) {
                    int col = w * 64 + ct * 16 + lr;
                    xhb[(size_t)row * HID + col] = f2bf(acc[rt][ct][r]);
                }
            }
}

// ---------------- attention scalars from bf16 xh ----------------
__global__ void k_att(const ushort* __restrict__ xhb, const float* __restrict__ att_s,
                      const float* __restrict__ att_d, float* __restrict__ a_s,
                      float* __restrict__ a_d, int Nn) {
    int idx = blockIdx.x * 256 + threadIdx.x;   // node*4 + h
    if (idx >= Nn * 4) return;
    int h = idx & 3;
    const ushort* xp = xhb + (size_t)idx * 64;
    const float* sp = att_s + h * 64;
    const float* dp = att_d + h * 64;
    float ss = 0.f, dd = 0.f;
#pragma unroll
    for (int q = 0; q < 8; ++q) {
        uint4 u = *(const uint4*)(xp + q * 8);
        float xv[8];
        xv[0] = __uint_as_float(u.x << 16); xv[1] = __uint_as_float(u.x & 0xffff0000u);
        xv[2] = __uint_as_float(u.y << 16); xv[3] = __uint_as_float(u.y & 0xffff0000u);
        xv[4] = __uint_as_float(u.z << 16); xv[5] = __uint_as_float(u.z & 0xffff0000u);
        xv[6] = __uint_as_float(u.w << 16); xv[7] = __uint_as_float(u.w & 0xffff0000u);
        float4 s0 = *(const float4*)(sp + q * 8);
        float4 s1 = *(const float4*)(sp + q * 8 + 4);
        float4 d0 = *(const float4*)(dp + q * 8);
        float4 d1 = *(const float4*)(dp + q * 8 + 4);
        ss += xv[0]*s0.x + xv[1]*s0.y + xv[2]*s0.z + xv[3]*s0.w
            + xv[4]*s1.x + xv[5]*s1.y + xv[6]*s1.z + xv[7]*s1.w;
        dd += xv[0]*d0.x + xv[1]*d0.y + xv[2]*d0.z + xv[3]*d0.w
            + xv[4]*d1.x + xv[5]*d1.y + xv[6]*d1.z + xv[7]*d1.w;
    }
    a_s[idx] = ss;
    a_d[idx] = dd;
}

// ---------------- CSR build ----------------
__global__ void k_hist(const int* __restrict__ dst, int E, int* cnt) {
    int e = blockIdx.x * 256 + threadIdx.x;
    if (e < E) atomicAdd(&cnt[dst[e]], 1);
}

__global__ void k_scan1(const int* __restrict__ cnt, int Nn, int* bsum) {
    int b = blockIdx.x, t = threadIdx.x;
    int idx = b * 256 + t;
    int v = (idx < Nn) ? cnt[idx] : 0;
#pragma unroll
    for (int off = 32; off; off >>= 1) v += __shfl_down(v, off);
    __shared__ int ws[4];
    if ((t & 63) == 0) ws[t >> 6] = v;
    __syncthreads();
    if (t == 0) bsum[b] = ws[0] + ws[1] + ws[2] + ws[3];
}

__global__ void k_scan2(int* bsum, int nb, int* total) {
    __shared__ int buf[256];
    int t = threadIdx.x;
    int v = (t < nb) ? bsum[t] : 0;
    buf[t] = v;
    __syncthreads();
    for (int off = 1; off < 256; off <<= 1) {
        int a = (t >= off) ? buf[t - off] : 0;
        __syncthreads();
        buf[t] += a;
        __syncthreads();
    }
    if (t < nb) bsum[t] = buf[t] - v;
    if (t == nb - 1) *total = buf[t];
}

__global__ void k_scan3(const int* __restrict__ cnt, int Nn, const int* __restrict__ bsum,
                        int* row_ptr, int* cursor) {
    __shared__ int buf[256];
    int b = blockIdx.x, t = threadIdx.x, idx = b * 256 + t;
    int v = (idx < Nn) ? cnt[idx] : 0;
    buf[t] = v;
    __syncthreads();
    for (int off = 1; off < 256; off <<= 1) {
        int a = (t >= off) ? buf[t - off] : 0;
        __syncthreads();
        buf[t] += a;
        __syncthreads();
    }
    if (idx < Nn) {
        int ex = bsum[b] + buf[t] - v;
        row_ptr[idx] = ex;
        cursor[idx] = ex;
    }
}

__global__ void k_scatter(const int* __restrict__ src, const int* __restrict__ dst,
                          int E, int* cursor, int* col) {
    int e = blockIdx.x * 256 + threadIdx.x;
    if (e < E) {
        int d = dst[e];
        int pos = atomicAdd(&cursor[d], 1);
        col[pos] = src[e];
    }
}

// ---------------- GAT aggregation: wave per node, single pass, no max-sub ----------------
__global__ __launch_bounds__(256) void k_gat(const int* __restrict__ row_ptr,
                                             const int* __restrict__ col,
                                             const ushort* __restrict__ xhb,
                                             const float* __restrict__ a_s,
                                             const float* __restrict__ a_d,
                                             const float* __restrict__ bias,
                                             float* __restrict__ hg, int Nn) {
    int w = threadIdx.x >> 6, lane = threadIdx.x & 63;
    int i = blockIdx.x * 4 + w;
    if (i >= Nn) return;
    int beg = row_ptr[i], end = row_ptr[i + 1];
    int q = lane >> 4, r = lane & 15;   // quarter q handles head q

    float adq = a_d[i * 4 + q];
    float asq = a_s[i * 4 + q];
    float ps = __expf(lrelu(asq + adq));   // self weight (unnormalized), head q

    // self term: channels lane*4..+3 belong to head q
    ushort4 sv = *(const ushort4*)(xhb + (size_t)i * HID + lane * 4);
    float4 acc;
    acc.x = ps * bf2f(sv.x); acc.y = ps * bf2f(sv.y);
    acc.z = ps * bf2f(sv.z); acc.w = ps * bf2f(sv.w);

    float dl = 0.f;
    for (int cb = beg; cb < end; cb += 64) {
        int n = end - cb; if (n > 64) n = 64;
        int c[4]; float p[4];
#pragma unroll
        for (int s = 0; s < 4; ++s) {
            int slot = s * 16 + r;
            bool valid = slot < n;
            c[s] = valid ? col[cb + slot] : 0;
            float pv = 0.f;
            if (valid) pv = __expf(lrelu(a_s[c[s] * 4 + q] + adq));
            p[s] = pv;
            dl += pv;
        }
#pragma unroll
        for (int s = 0; s < 4; ++s) {
            int base = s * 16;
            if (base >= n) break;
            int m_ = n - base; if (m_ > 16) m_ = 16;
#pragma unroll 4
            for (int jj = 0; jj < m_; ++jj) {
                int srcl = (lane & 48) + jj;
                int cj   = __shfl(c[s], srcl);
                float pj = __shfl(p[s], srcl);
                ushort4 xv = *(const ushort4*)(xhb + (size_t)cj * HID + lane * 4);
                acc.x += pj * bf2f(xv.x);
                acc.y += pj * bf2f(xv.y);
                acc.z += pj * bf2f(xv.z);
                acc.w += pj * bf2f(xv.w);
            }
        }
    }

    // reduce denominator within quarter (16 lanes, all head q)
#pragma unroll
    for (int off = 8; off; off >>= 1) dl += __shfl_xor(dl, off);
    float inv = 1.f / (dl + ps + 1e-16f);

    float4 b4 = *(const float4*)(bias + lane * 4);
    float4 o;
    o.x = acc.x * inv + b4.x;
    o.y = acc.y * inv + b4.y;
    o.z = acc.z * inv + b4.z;
    o.w = acc.w * inv + b4.w;
    *(float4*)(hg + (size_t)i * HID + lane * 4) = o;
}

// ---------------- BN stats (2-level) ----------------
__global__ void k_bnstat(const float* __restrict__ h, int Nn, int C,
                         float* __restrict__ sums) {
    int t = threadIdx.x;
    int rows_per = (Nn + gridDim.x - 1) / gridDim.x;
    int r0 = blockIdx.x * rows_per;
    int r1 = min(Nn, r0 + rows_per);
    float s = 0.f, sq = 0.f;
    for (int r = r0; r < r1; ++r) {
        float v = h[(size_t)r * C + t];
        s += v;
        sq += v * v;
    }
    atomicAdd(&sums[t], s);
    atomicAdd(&sums[C + t], sq);
}

__global__ void k_bnfin(const float* __restrict__ sums, int C, float Ninv,
                        const float* __restrict__ gamma, const float* __restrict__ beta,
                        float* __restrict__ scale, float* __restrict__ shift) {
    int t = threadIdx.x;
    if (t >= C) return;
    float mu = sums[t] * Ninv;
    float var = sums[C + t] * Ninv - mu * mu;
    float a = gamma[t] * rsqrtf(var + 1e-5f);
    scale[t] = a;
    shift[t] = beta[t] - mu * a;
}

// ---------------- MFMA Linear: h2 = relu(bn1(hg)) @ Wl + bl ----------------
__global__ __launch_bounds__(256) void k_lin(const float* __restrict__ hg,
                                             const float* __restrict__ sc1,
                                             const float* __restrict__ sf1,
                                             const ushort* __restrict__ Wlt,
                                             const float* __restrict__ bl,
                                             float* __restrict__ h2, int Nn) {
    __shared__ ushort Alds[128][264];   // 128 rows x 256 k (+8 pad), bf16 of relu(bn1(hg))
    int t = threadIdx.x;
    int w = t >> 6, lane = t & 63;
    int row0 = blockIdx.x * 128;

    // stage + BN1 + ReLU + cast
    for (int i = t; i < 128 * 64; i += 256) {
        int rr = i >> 6, c4 = i & 63;
        int gr = row0 + rr;
        ushort4 o = make_ushort4(0, 0, 0, 0);
        if (gr < Nn) {
            float4 v = *(const float4*)(hg + (size_t)gr * HID + c4 * 4);
            float4 s = *(const float4*)(sc1 + c4 * 4);
            float4 f = *(const float4*)(sf1 + c4 * 4);
            v.x = fmaxf(v.x * s.x + f.x, 0.f);
            v.y = fmaxf(v.y * s.y + f.y, 0.f);
            v.z = fmaxf(v.z * s.z + f.z, 0.f);
            v.w = fmaxf(v.w * s.w + f.w, 0.f);
            o = make_ushort4(f2bf(v.x), f2bf(v.y), f2bf(v.z), f2bf(v.w));
        }
        *(ushort4*)(&Alds[rr][c4 * 4]) = o;
    }
    __syncthreads();

    int qw = lane >> 4, lr = lane & 15;
    f32x4 zero = {0.f, 0.f, 0.f, 0.f};
    f32x4 acc[2][4];
#pragma unroll
    for (int a = 0; a < 2; ++a)
#pragma unroll
        for (int b = 0; b < 4; ++b) acc[a][b] = zero;

#pragma unroll
    for (int kt = 0; kt < 8; ++kt) {
        bf16x8 a0 = *(const bf16x8*)(&Alds[w * 32 + lr][kt * 32 + qw * 8]);
        bf16x8 a1 = *(const bf16x8*)(&Alds[w * 32 + 16 + lr][kt * 32 + qw * 8]);
#pragma unroll
        for (int ct = 0; ct < 4; ++ct) {
            bf16x8 b = *(const bf16x8*)(Wlt + (size_t)(ct * 16 + lr) * HID + kt * 32 + qw * 8);
            acc[0][ct] = __builtin_amdgcn_mfma_f32_16x16x32_bf16(a0, b, acc[0][ct], 0, 0, 0);
            acc[1][ct] = __builtin_amdgcn_mfma_f32_16x16x32_bf16(a1, b, acc[1][ct], 0, 0, 0);
        }
    }

#pragma unroll
    for (int ct = 0; ct < 4; ++ct) {
        float blc = bl[ct * 16 + lr];
#pragma unroll
        for (int rt = 0; rt < 2; ++rt)
#pragma unroll
            for (int r = 0; r < 4; ++r) {
                int row = row0 + w * 32 + rt * 16 + qw * 4 + r;
                if (row < Nn) h2[(size_t)row * OUT_F + ct * 16 + lr] = acc[rt][ct][r] + blc;
            }
    }
}

// ---------------- final BN2 apply + relu ----------------
__global__ void k_out(const float* __restrict__ h2, const float* __restrict__ scale2,
                      const float* __restrict__ shift2, float* __restrict__ out, int total) {
    int i = blockIdx.x * 256 + threadIdx.x;
    if (i >= total) return;
    int c = i & 63;
    float v = h2[i] * scale2[c] + shift2[c];
    out[i] = v > 0.f ? v : 0.f;
}

extern "C" void kernel_launch(void* const* d_in, const int* in_sizes, int n_in,
                              void* d_out, int out_size, void* d_ws, size_t ws_size,
                              hipStream_t stream) {
    const float* x     = (const float*)d_in[0];
    const float* Wg    = (const float*)d_in[2];
    const float* att_s = (const float*)d_in[3];
    const float* att_d = (const float*)d_in[4];
    const float* bias_g= (const float*)d_in[5];
    const float* g1    = (const float*)d_in[6];
    const float* b1    = (const float*)d_in[7];
    const float* Wl    = (const float*)d_in[8];
    const float* bl    = (const float*)d_in[9];
    const float* g2    = (const float*)d_in[10];
    const float* b2    = (const float*)d_in[11];
    const int*   ei    = (const int*)d_in[12];

    const int N = in_sizes[0] / IN_F;
    const int E = in_sizes[12] / 2;
    const int* e_src = ei;
    const int* e_dst = ei + E;
    const int NB = (N + 255) / 256;

    char* wsb = (char*)d_ws;
    size_t o = 0;
    auto take = [&](size_t bytes) -> void* {
        void* p = wsb + o;
        o = (o + bytes + 255) & ~(size_t)255;
        return p;
    };
    ushort* xb     = (ushort*)take((size_t)N * IN_F * 2);
    ushort* xhb    = (ushort*)take((size_t)N * HID * 2);
    ushort* Wgt    = (ushort*)take((size_t)IN_F * HID * 2);
    ushort* Wlt    = (ushort*)take((size_t)OUT_F * HID * 2);
    float*  hg     = (float*)take((size_t)N * HID * 4);
    float*  h2     = (float*)take((size_t)N * OUT_F * 4);
    float*  a_s    = (float*)take((size_t)N * 4 * 4);
    float*  a_d    = (float*)take((size_t)N * 4 * 4);
    int*    row_ptr= (int*)take((size_t)(N + 1) * 4);
    int*    cnt    = (int*)take((size_t)N * 4);
    int*    cursor = (int*)take((size_t)N * 4);
    int*    colidx = (int*)take((size_t)E * 4);
    int*    bsum   = (int*)take((size_t)NB * 4);
    float*  stats  = (float*)take(2048 * 4);
    float* bn1s = stats;
    float* bn2s = stats + 512;
    float* sc1  = stats + 640;
    float* sf1  = stats + 896;
    float* sc2  = stats + 1152;
    float* sf2  = stats + 1216;

    float* out = (float*)d_out;

    k_init<<<NB, 256, 0, stream>>>(cnt, N, stats, 640);
    k_cast_x<<<(N * IN_F / 4 + 255) / 256, 256, 0, stream>>>(x, xb, N * IN_F / 4);
    k_cast_w<<<(IN_F * HID + OUT_F * HID + 255) / 256, 256, 0, stream>>>(Wg, Wl, Wgt, Wlt);
    k_gemm_xh<<<(N + 63) / 64, 256, 0, stream>>>(xb, Wgt, xhb, N);
    k_att<<<(N * 4 + 255) / 256, 256, 0, stream>>>(xhb, att_s, att_d, a_s, a_d, N);
    k_hist<<<(E + 255) / 256, 256, 0, stream>>>(e_dst, E, cnt);
    k_scan1<<<NB, 256, 0, stream>>>(cnt, N, bsum);
    k_scan2<<<1, 256, 0, stream>>>(bsum, NB, row_ptr + N);
    k_scan3<<<NB, 256, 0, stream>>>(cnt, N, bsum, row_ptr, cursor);
    k_scatter<<<(E + 255) / 256, 256, 0, stream>>>(e_src, e_dst, E, cursor, colidx);
    k_gat<<<(N + 3) / 4, 256, 0, stream>>>(row_ptr, colidx, xhb, a_s, a_d, bias_g, hg, N);
    k_bnstat<<<256, HID, 0, stream>>>(hg, N, HID, bn1s);
    k_bnfin<<<1, HID, 0, stream>>>(bn1s, HID, 1.0f / N, g1, b1, sc1, sf1);
    k_lin<<<(N + 127) / 128, 256, 0, stream>>>(hg, sc1, sf1, Wlt, bl, h2, N);
    k_bnstat<<<256, OUT_F, 0, stream>>>(h2, N, OUT_F, bn2s);
    k_bnfin<<<1, OUT_F, 0, stream>>>(bn2s, OUT_F, 1.0f / N, g2, b2, sc2, sf2);
    k_out<<<(N * OUT_F + 255) / 256, 256, 0, stream>>>(h2, sc2, sf2, out, N * OUT_F);
}

// Round 5
// 253.657 us; speedup vs baseline: 2.5070x; 1.4321x over previous
//
#include <hip/hip_runtime.h>
#include <hip/hip_bf16.h>

#define IN_F 128
#define HID 256
#define OUT_F 64
#define NEG 0.2f

typedef __attribute__((ext_vector_type(8))) short bf16x8;
typedef __attribute__((ext_vector_type(4))) float f32x4;

__device__ __forceinline__ float lrelu(float v) { return v > 0.f ? v : NEG * v; }
__device__ __forceinline__ float bf2f(ushort u) { return __uint_as_float((uint)u << 16); }
__device__ __forceinline__ ushort f2bf(float f) {
    uint i = __float_as_uint(f);
    i += 0x7fffu + ((i >> 16) & 1u);
    return (ushort)(i >> 16);
}

// ---------------- init: zero cnt/stats + transpose/cast weights ----------------
__global__ void k_init(const float* __restrict__ Wg, const float* __restrict__ Wl,
                       ushort* __restrict__ Wgt, ushort* __restrict__ Wlt,
                       int* cnt, int Nn, float* stats) {
    int i = blockIdx.x * 256 + threadIdx.x;
    if (i < Nn) cnt[i] = 0;
    if (i < 640) stats[i] = 0.f;              // [0..511] bn1 sum/sq, [512..639] bn2 sum/sq
    if (i < IN_F * HID) {                     // Wgt[c][k] = Wg[k][c]
        int c = i >> 7, k = i & 127;
        Wgt[i] = f2bf(Wg[k * HID + c]);
    }
    if (i < OUT_F * HID) {                    // Wlt[c][k] = Wl[k][c]
        int c = i >> 8, k = i & 255;
        Wlt[i] = f2bf(Wl[k * OUT_F + c]);
    }
}

// ------- fused: cast x -> MFMA GEMM -> xhb(bf16) + attention scalars a_s/a_d -------
__global__ __launch_bounds__(256) void k_gemm_att(const float* __restrict__ x,
                                                  const ushort* __restrict__ Wgt,
                                                  const float* __restrict__ att_s,
                                                  const float* __restrict__ att_d,
                                                  ushort* __restrict__ xhb,
                                                  float* __restrict__ a_s,
                                                  float* __restrict__ a_d, int Nn) {
    __shared__ ushort Alds[64][136];   // 64 rows x 128 k (+8 pad)
    int t = threadIdx.x;
    int w = t >> 6, lane = t & 63;
    int row0 = blockIdx.x * 64;

    // stage A: read fp32 x, cast to bf16.  2048 float4 chunks (64 rows x 32)
    for (int i = t; i < 2048; i += 256) {
        int r = i >> 5, c = i & 31;
        int gr = row0 + r;
        float4 v = make_float4(0.f, 0.f, 0.f, 0.f);
        if (gr < Nn) v = *(const float4*)(x + (size_t)gr * IN_F + c * 4);
        *(ushort4*)(&Alds[r][c * 4]) = make_ushort4(f2bf(v.x), f2bf(v.y), f2bf(v.z), f2bf(v.w));
    }

    int qw = lane >> 4, lr = lane & 15;
    // B-frags: wave w covers cols [64w, 64w+64) == head w
    bf16x8 bf[4][4];
#pragma unroll
    for (int ct = 0; ct < 4; ++ct)
#pragma unroll
        for (int kt = 0; kt < 4; ++kt) {
            int col = w * 64 + ct * 16 + lr;
            bf[ct][kt] = *(const bf16x8*)(Wgt + (size_t)col * IN_F + kt * 32 + qw * 8);
        }

    f32x4 zero = {0.f, 0.f, 0.f, 0.f};
    f32x4 acc[4][4];
#pragma unroll
    for (int rt = 0; rt < 4; ++rt)
#pragma unroll
        for (int ct = 0; ct < 4; ++ct) acc[rt][ct] = zero;

    __syncthreads();
#pragma unroll
    for (int kt = 0; kt < 4; ++kt) {
#pragma unroll
        for (int rt = 0; rt < 4; ++rt) {
            bf16x8 af = *(const bf16x8*)(&Alds[rt * 16 + lr][kt * 32 + qw * 8]);
#pragma unroll
            for (int ct = 0; ct < 4; ++ct)
                acc[rt][ct] = __builtin_amdgcn_mfma_f32_16x16x32_bf16(af, bf[ct][kt], acc[rt][ct], 0, 0, 0);
        }
    }

    // att vectors for head w, this lane's lr slice
    float asv[4], adv[4];
#pragma unroll
    for (int ct = 0; ct < 4; ++ct) {
        asv[ct] = att_s[w * 64 + ct * 16 + lr];
        adv[ct] = att_d[w * 64 + ct * 16 + lr];
    }

    // epilogue: write xhb bf16 + reduce a_s/a_d per row (16-lane group reduce)
#pragma unroll
    for (int rt = 0; rt < 4; ++rt)
#pragma unroll
        for (int r = 0; r < 4; ++r) {
            int row = row0 + rt * 16 + qw * 4 + r;
            float ss = 0.f, dd = 0.f;
#pragma unroll
            for (int ct = 0; ct < 4; ++ct) {
                float v = acc[rt][ct][r];
                ss += v * asv[ct];
                dd += v * adv[ct];
                if (row < Nn) xhb[(size_t)row * HID + w * 64 + ct * 16 + lr] = f2bf(v);
            }
#pragma unroll
            for (int off = 1; off < 16; off <<= 1) {
                ss += __shfl_xor(ss, off);
                dd += __shfl_xor(dd, off);
            }
            if (row < Nn && lr == 0) {
                a_s[row * 4 + w] = ss;
                a_d[row * 4 + w] = dd;
            }
        }
}

// ---------------- CSR build ----------------
__global__ void k_hist(const int* __restrict__ dst, int E, int* cnt) {
    int e = blockIdx.x * 256 + threadIdx.x;
    if (e < E) atomicAdd(&cnt[dst[e]], 1);
}

__global__ void k_scan1(const int* __restrict__ cnt, int Nn, int* bsum) {
    int b = blockIdx.x, t = threadIdx.x;
    int idx = b * 256 + t;
    int v = (idx < Nn) ? cnt[idx] : 0;
#pragma unroll
    for (int off = 32; off; off >>= 1) v += __shfl_down(v, off);
    __shared__ int ws[4];
    if ((t & 63) == 0) ws[t >> 6] = v;
    __syncthreads();
    if (t == 0) bsum[b] = ws[0] + ws[1] + ws[2] + ws[3];
}

__global__ void k_scan2(int* bsum, int nb, int* total) {
    __shared__ int buf[256];
    int t = threadIdx.x;
    int v = (t < nb) ? bsum[t] : 0;
    buf[t] = v;
    __syncthreads();
    for (int off = 1; off < 256; off <<= 1) {
        int a = (t >= off) ? buf[t - off] : 0;
        __syncthreads();
        buf[t] += a;
        __syncthreads();
    }
    if (t < nb) bsum[t] = buf[t] - v;
    if (t == nb - 1) *total = buf[t];
}

__global__ void k_scan3(const int* __restrict__ cnt, int Nn, const int* __restrict__ bsum,
                        int* row_ptr, int* cursor) {
    __shared__ int buf[256];
    int b = blockIdx.x, t = threadIdx.x, idx = b * 256 + t;
    int v = (idx < Nn) ? cnt[idx] : 0;
    buf[t] = v;
    __syncthreads();
    for (int off = 1; off < 256; off <<= 1) {
        int a = (t >= off) ? buf[t - off] : 0;
        __syncthreads();
        buf[t] += a;
        __syncthreads();
    }
    if (idx < Nn) {
        int ex = bsum[b] + buf[t] - v;
        row_ptr[idx] = ex;
        cursor[idx] = ex;
    }
}

__global__ void k_scatter(const int* __restrict__ src, const int* __restrict__ dst,
                          int E, int* cursor, int* col) {
    int e = blockIdx.x * 256 + threadIdx.x;
    if (e < E) {
        int d = dst[e];
        int pos = atomicAdd(&cursor[d], 1);
        col[pos] = src[e];
    }
}

// ---------------- GAT aggregation: wave per node -> hgb (bf16) ----------------
__global__ __launch_bounds__(256) void k_gat(const int* __restrict__ row_ptr,
                                             const int* __restrict__ col,
                                             const ushort* __restrict__ xhb,
                                             const float* __restrict__ a_s,
                                             const float* __restrict__ a_d,
                                             const float* __restrict__ bias,
                                             ushort* __restrict__ hgb, int Nn) {
    int w = threadIdx.x >> 6, lane = threadIdx.x & 63;
    int i = blockIdx.x * 4 + w;
    if (i >= Nn) return;
    int beg = row_ptr[i], end = row_ptr[i + 1];
    int q = lane >> 4, r = lane & 15;   // quarter q handles head q

    float adq = a_d[i * 4 + q];
    float asq = a_s[i * 4 + q];
    float ps = __expf(lrelu(asq + adq));

    ushort4 sv = *(const ushort4*)(xhb + (size_t)i * HID + lane * 4);
    float4 acc;
    acc.x = ps * bf2f(sv.x); acc.y = ps * bf2f(sv.y);
    acc.z = ps * bf2f(sv.z); acc.w = ps * bf2f(sv.w);

    float dl = 0.f;
    for (int cb = beg; cb < end; cb += 64) {
        int n = end - cb; if (n > 64) n = 64;
        int c[4]; float p[4];
#pragma unroll
        for (int s = 0; s < 4; ++s) {
            int slot = s * 16 + r;
            bool valid = slot < n;
            c[s] = valid ? col[cb + slot] : 0;
            float pv = 0.f;
            if (valid) pv = __expf(lrelu(a_s[c[s] * 4 + q] + adq));
            p[s] = pv;
            dl += pv;
        }
#pragma unroll
        for (int s = 0; s < 4; ++s) {
            int base = s * 16;
            if (base >= n) break;
            int m_ = n - base; if (m_ > 16) m_ = 16;
#pragma unroll 4
            for (int jj = 0; jj < m_; ++jj) {
                int srcl = (lane & 48) + jj;
                int cj   = __shfl(c[s], srcl);
                float pj = __shfl(p[s], srcl);
                ushort4 xv = *(const ushort4*)(xhb + (size_t)cj * HID + lane * 4);
                acc.x += pj * bf2f(xv.x);
                acc.y += pj * bf2f(xv.y);
                acc.z += pj * bf2f(xv.z);
                acc.w += pj * bf2f(xv.w);
            }
        }
    }

#pragma unroll
    for (int off = 8; off; off >>= 1) dl += __shfl_xor(dl, off);
    float inv = 1.f / (dl + ps + 1e-16f);

    float4 b4 = *(const float4*)(bias + lane * 4);
    ushort4 o;
    o.x = f2bf(acc.x * inv + b4.x);
    o.y = f2bf(acc.y * inv + b4.y);
    o.z = f2bf(acc.z * inv + b4.z);
    o.w = f2bf(acc.w * inv + b4.w);
    *(ushort4*)(hgb + (size_t)i * HID + lane * 4) = o;
}

// ---------------- BN1 stats from bf16 hgb ----------------
__global__ __launch_bounds__(256) void k_bnstat1(const ushort* __restrict__ hgb, int Nn,
                                                 float* __restrict__ sums) {
    __shared__ float sbuf[512];
    int t = threadIdx.x;
    sbuf[t] = 0.f; sbuf[t + 256] = 0.f;
    __syncthreads();
    int c0 = (t & 31) * 8;
    float s[8] = {}, sq[8] = {};
    for (int row = blockIdx.x * 8 + (t >> 5); row < Nn; row += gridDim.x * 8) {
        uint4 u = *(const uint4*)(hgb + (size_t)row * HID + c0);
        uint uu[4] = {u.x, u.y, u.z, u.w};
#pragma unroll
        for (int p = 0; p < 4; ++p) {
            float v0 = __uint_as_float(uu[p] << 16);
            float v1 = __uint_as_float(uu[p] & 0xffff0000u);
            s[p * 2] += v0;  sq[p * 2] += v0 * v0;
            s[p * 2 + 1] += v1; sq[p * 2 + 1] += v1 * v1;
        }
    }
#pragma unroll
    for (int j = 0; j < 8; ++j) {
        atomicAdd(&sbuf[c0 + j], s[j]);
        atomicAdd(&sbuf[256 + c0 + j], sq[j]);
    }
    __syncthreads();
    atomicAdd(&sums[t], sbuf[t]);
    atomicAdd(&sums[256 + t], sbuf[t + 256]);
}

// ------- fused: bnfin1 + MFMA Linear + h2b(bf16) + BN2 stats -------
__global__ __launch_bounds__(256) void k_lin(const ushort* __restrict__ hgb,
                                             const float* __restrict__ bn1s, float Ninv,
                                             const float* __restrict__ g1, const float* __restrict__ b1,
                                             const ushort* __restrict__ Wlt,
                                             const float* __restrict__ bl,
                                             ushort* __restrict__ h2b,
                                             float* __restrict__ bn2s, int Nn) {
    __shared__ ushort Alds[128][264];
    __shared__ float sc1[256], sf1[256];
    __shared__ float sbuf2[128];
    int t = threadIdx.x;
    int w = t >> 6, lane = t & 63;
    int row0 = blockIdx.x * 128;

    // bnfin1 inline (each block, trivially cheap)
    {
        float mu = bn1s[t] * Ninv;
        float var = bn1s[256 + t] * Ninv - mu * mu;
        float a = g1[t] * rsqrtf(var + 1e-5f);
        sc1[t] = a; sf1[t] = b1[t] - mu * a;
    }
    if (t < 128) sbuf2[t] = 0.f;
    __syncthreads();

    // stage: BN1 + ReLU + bf16, from bf16 hgb.  4096 uint4 chunks (128 rows x 32)
    for (int i = t; i < 4096; i += 256) {
        int rr = i >> 5, c8 = (i & 31) * 8;
        int gr = row0 + rr;
        ushort ob[8] = {0, 0, 0, 0, 0, 0, 0, 0};
        if (gr < Nn) {
            uint4 u = *(const uint4*)(hgb + (size_t)gr * HID + c8);
            uint uu[4] = {u.x, u.y, u.z, u.w};
#pragma unroll
            for (int p = 0; p < 4; ++p) {
                float v0 = __uint_as_float(uu[p] << 16);
                float v1 = __uint_as_float(uu[p] & 0xffff0000u);
                int cA = c8 + p * 2, cB = c8 + p * 2 + 1;
                v0 = fmaxf(v0 * sc1[cA] + sf1[cA], 0.f);
                v1 = fmaxf(v1 * sc1[cB] + sf1[cB], 0.f);
                ob[p * 2] = f2bf(v0);
                ob[p * 2 + 1] = f2bf(v1);
            }
        }
        *(ushort4*)(&Alds[rr][c8]) = make_ushort4(ob[0], ob[1], ob[2], ob[3]);
        *(ushort4*)(&Alds[rr][c8 + 4]) = make_ushort4(ob[4], ob[5], ob[6], ob[7]);
    }
    __syncthreads();

    int qw = lane >> 4, lr = lane & 15;
    f32x4 zero = {0.f, 0.f, 0.f, 0.f};
    f32x4 acc[2][4];
#pragma unroll
    for (int a = 0; a < 2; ++a)
#pragma unroll
        for (int b = 0; b < 4; ++b) acc[a][b] = zero;

#pragma unroll
    for (int kt = 0; kt < 8; ++kt) {
        bf16x8 a0 = *(const bf16x8*)(&Alds[w * 32 + lr][kt * 32 + qw * 8]);
        bf16x8 a1 = *(const bf16x8*)(&Alds[w * 32 + 16 + lr][kt * 32 + qw * 8]);
#pragma unroll
        for (int ct = 0; ct < 4; ++ct) {
            bf16x8 b = *(const bf16x8*)(Wlt + (size_t)(ct * 16 + lr) * HID + kt * 32 + qw * 8);
            acc[0][ct] = __builtin_amdgcn_mfma_f32_16x16x32_bf16(a0, b, acc[0][ct], 0, 0, 0);
            acc[1][ct] = __builtin_amdgcn_mfma_f32_16x16x32_bf16(a1, b, acc[1][ct], 0, 0, 0);
        }
    }

    // epilogue: write h2b bf16 + per-block BN2 partial sums
#pragma unroll
    for (int ct = 0; ct < 4; ++ct) {
        float blc = bl[ct * 16 + lr];
        float s2 = 0.f, q2 = 0.f;
#pragma unroll
        for (int rt = 0; rt < 2; ++rt)
#pragma unroll
            for (int r = 0; r < 4; ++r) {
                int row = row0 + w * 32 + rt * 16 + qw * 4 + r;
                if (row < Nn) {
                    ushort u = f2bf(acc[rt][ct][r] + blc);
                    h2b[(size_t)row * OUT_F + ct * 16 + lr] = u;
                    float vr = bf2f(u);
                    s2 += vr; q2 += vr * vr;
                }
            }
        atomicAdd(&sbuf2[ct * 16 + lr], s2);
        atomicAdd(&sbuf2[64 + ct * 16 + lr], q2);
    }
    __syncthreads();
    if (t < 128) atomicAdd(&bn2s[t], sbuf2[t]);
}

// ---------------- fused bnfin2 + BN2 apply + relu -> out ----------------
__global__ __launch_bounds__(256) void k_out(const ushort* __restrict__ h2b,
                                             const float* __restrict__ bn2s, float Ninv,
                                             const float* __restrict__ g2, const float* __restrict__ b2,
                                             float* __restrict__ out, int Nn) {
    __shared__ float sc[64], sf[64];
    int t = threadIdx.x;
    if (t < 64) {
        float mu = bn2s[t] * Ninv;
        float var = bn2s[64 + t] * Ninv - mu * mu;
        float a = g2[t] * rsqrtf(var + 1e-5f);
        sc[t] = a; sf[t] = b2[t] - mu * a;
    }
    __syncthreads();
    int total8 = Nn * 8;   // uint4 groups of 8 channels
    for (int i = blockIdx.x * 256 + t; i < total8; i += gridDim.x * 256) {
        uint4 u = ((const uint4*)h2b)[i];
        int c0 = (i & 7) * 8;
        uint uu[4] = {u.x, u.y, u.z, u.w};
        float o[8];
#pragma unroll
        for (int p = 0; p < 4; ++p) {
            float v0 = __uint_as_float(uu[p] << 16);
            float v1 = __uint_as_float(uu[p] & 0xffff0000u);
            o[p * 2] = fmaxf(v0 * sc[c0 + p * 2] + sf[c0 + p * 2], 0.f);
            o[p * 2 + 1] = fmaxf(v1 * sc[c0 + p * 2 + 1] + sf[c0 + p * 2 + 1], 0.f);
        }
        float4* op = (float4*)(out + (size_t)i * 8);
        op[0] = make_float4(o[0], o[1], o[2], o[3]);
        op[1] = make_float4(o[4], o[5], o[6], o[7]);
    }
}

extern "C" void kernel_launch(void* const* d_in, const int* in_sizes, int n_in,
                              void* d_out, int out_size, void* d_ws, size_t ws_size,
                              hipStream_t stream) {
    const float* x     = (const float*)d_in[0];
    const float* Wg    = (const float*)d_in[2];
    const float* att_s = (const float*)d_in[3];
    const float* att_d = (const float*)d_in[4];
    const float* bias_g= (const float*)d_in[5];
    const float* g1    = (const float*)d_in[6];
    const float* b1    = (const float*)d_in[7];
    const float* Wl    = (const float*)d_in[8];
    const float* bl    = (const float*)d_in[9];
    const float* g2    = (const float*)d_in[10];
    const float* b2    = (const float*)d_in[11];
    const int*   ei    = (const int*)d_in[12];

    const int N = in_sizes[0] / IN_F;
    const int E = in_sizes[12] / 2;
    const int* e_src = ei;
    const int* e_dst = ei + E;
    const int NB = (N + 255) / 256;

    char* wsb = (char*)d_ws;
    size_t o = 0;
    auto take = [&](size_t bytes) -> void* {
        void* p = wsb + o;
        o = (o + bytes + 255) & ~(size_t)255;
        return p;
    };
    ushort* xhb    = (ushort*)take((size_t)N * HID * 2);
    ushort* hgb    = (ushort*)take((size_t)N * HID * 2);
    ushort* h2b    = (ushort*)take((size_t)N * OUT_F * 2);
    ushort* Wgt    = (ushort*)take((size_t)IN_F * HID * 2);
    ushort* Wlt    = (ushort*)take((size_t)OUT_F * HID * 2);
    float*  a_s    = (float*)take((size_t)N * 4 * 4);
    float*  a_d    = (float*)take((size_t)N * 4 * 4);
    int*    row_ptr= (int*)take((size_t)(N + 1) * 4);
    int*    cnt    = (int*)take((size_t)N * 4);
    int*    cursor = (int*)take((size_t)N * 4);
    int*    colidx = (int*)take((size_t)E * 4);
    int*    bsum   = (int*)take((size_t)NB * 4);
    float*  stats  = (float*)take(1024 * 4);
    float* bn1s = stats;          // [0..511]
    float* bn2s = stats + 512;    // [512..639]

    float* out = (float*)d_out;
    float Ninv = 1.0f / (float)N;

    k_init<<<NB, 256, 0, stream>>>(Wg, Wl, Wgt, Wlt, cnt, N, stats);
    k_gemm_att<<<(N + 63) / 64, 256, 0, stream>>>(x, Wgt, att_s, att_d, xhb, a_s, a_d, N);
    k_hist<<<(E + 255) / 256, 256, 0, stream>>>(e_dst, E, cnt);
    k_scan1<<<NB, 256, 0, stream>>>(cnt, N, bsum);
    k_scan2<<<1, 256, 0, stream>>>(bsum, NB, row_ptr + N);
    k_scan3<<<NB, 256, 0, stream>>>(cnt, N, bsum, row_ptr, cursor);
    k_scatter<<<(E + 255) / 256, 256, 0, stream>>>(e_src, e_dst, E, cursor, colidx);
    k_gat<<<(N + 3) / 4, 256, 0, stream>>>(row_ptr, colidx, xhb, a_s, a_d, bias_g, hgb, N);
    k_bnstat1<<<256, 256, 0, stream>>>(hgb, N, bn1s);
    k_lin<<<(N + 127) / 128, 256, 0, stream>>>(hgb, bn1s, Ninv, g1, b1, Wlt, bl, h2b, bn2s, N);
    k_out<<<1024, 256, 0, stream>>>(h2b, bn2s, Ninv, g2, b2, out, N);
}